// Round 5
// baseline (740.668 us; speedup 1.0000x reference)
//
#include <hip/hip_runtime.h>
#include <hip/hip_bf16.h>

typedef __bf16 bf16_t;
typedef __bf16 bf16x8 __attribute__((ext_vector_type(8)));
typedef float f32x4 __attribute__((ext_vector_type(4)));

__device__ __forceinline__ float ldin(const void* p, long i, int isbf) {
  if (isbf) {
    unsigned short u = ((const unsigned short*)p)[i];
    unsigned int w = ((unsigned int)u) << 16;
    float f; __builtin_memcpy(&f, &w, 4); return f;
  }
  return ((const float*)p)[i];
}

__device__ __forceinline__ bf16_t f2b(float f) {
  unsigned int u; __builtin_memcpy(&u, &f, 4);
  u += 0x7FFFu + ((u >> 16) & 1u);
  unsigned short h = (unsigned short)(u >> 16);
  bf16_t r; __builtin_memcpy(&r, &h, 2); return r;
}

__device__ __forceinline__ float b2f(bf16_t b) {
  unsigned short h; __builtin_memcpy(&h, &b, 2);
  unsigned int u = ((unsigned int)h) << 16;
  float f; __builtin_memcpy(&f, &u, 4); return f;
}

__device__ __forceinline__ float bb2f(unsigned short h) {
  unsigned int u = ((unsigned int)h) << 16;
  float f; __builtin_memcpy(&f, &u, 4); return f;
}

__device__ __forceinline__ unsigned short bbits(bf16_t b) {
  unsigned short h; __builtin_memcpy(&h, &b, 2); return h;
}

__device__ __forceinline__ void ld4(const void* p, long i, int isbf, float* v) {
  if (isbf) {
    ushort4 u = *(const ushort4*)((const unsigned short*)p + i);
    v[0] = bb2f(u.x); v[1] = bb2f(u.y); v[2] = bb2f(u.z); v[3] = bb2f(u.w);
  } else {
    float4 f = *(const float4*)((const float*)p + i);
    v[0] = f.x; v[1] = f.y; v[2] = f.z; v[3] = f.w;
  }
}

__device__ __forceinline__ f32x4 mfma(bf16x8 a, bf16x8 b, f32x4 c) {
  return __builtin_amdgcn_mfma_f32_16x16x32_bf16(a, b, c, 0, 0, 0);
}

// Raw barrier: drains LDS ops only; global prefetch loads ride through.
// The compiler's register-dependency tracking inserts exact counted vmcnt
// waits where prefetched regs are consumed (auto T3/T4).
__device__ __forceinline__ void lbar() {
  asm volatile("s_waitcnt lgkmcnt(0)\n\ts_barrier" ::: "memory");
}

// ---- dtype detector ----
__global__ void kdetect(const unsigned int* x, int* flag) {
  __shared__ int cnt;
  if (threadIdx.x == 0) cnt = 0;
  __syncthreads();
  int local = 0;
  for (int k = 0; k < 4; ++k) {
    unsigned int u = x[threadIdx.x * 4 + k];
    unsigned int e = (u >> 7) & 0xFFu;
    if (e >= 116u && e <= 133u) local++;
  }
  atomicAdd(&cnt, local);
  __syncthreads();
  if (threadIdx.x == 0) *flag = (cnt > 512) ? 1 : 0;
}

// ---- K0: weight conversion + BN folding ----
__global__ void k0(const void* thw_f, const void* phw, const void* gw, const void* ww_f,
                   const void* wb, const void* gma, const void* bta, const void* mean,
                   const void* var, bf16_t* thwb, bf16_t* phwb, bf16_t* gwb, bf16_t* wwb,
                   float* scw, float* shw, const int* flag) {
  int isbf = *flag;
  int i = blockIdx.x * 256 + threadIdx.x;
  thwb[i] = f2b(ldin(thw_f, i, isbf));
  phwb[i] = f2b(ldin(phw, i, isbf));
  gwb[i]  = f2b(ldin(gw, i, isbf));
  wwb[i]  = f2b(ldin(ww_f, i, isbf));
  if (i < 256) {
    float s = ldin(gma, i, isbf) * rsqrtf(ldin(var, i, isbf) + 1e-5f);
    scw[i] = s;
    shw[i] = (ldin(wb, i, isbf) - ldin(mean, i, isbf)) * s + ldin(bta, i, isbf);
  }
}

// ---- K1: unchanged from r4 (passing, ~85us; edits were null twice) ----
__global__ __launch_bounds__(256) void k1(const void* xin, const bf16_t* phwb,
    const bf16_t* gwb, const void* phb, const void* gbb,
    bf16_t* phiH, bf16_t* phiL, bf16_t* gT, const int* flag) {
  int isbf = *flag;
  int wg = blockIdx.x;
  int tile = wg >> 4, j = wg & 15;
  int bi = tile >> 4, t16 = tile & 15, ty = t16 >> 2, tx = t16 & 3;
  long xb = (long)bi * 256 * 16384 + (long)(ty * 32 + 2 * j) * 128 + tx * 32;

  __shared__ __align__(16) bf16_t sX[64 * 256];
  __shared__ __align__(16) bf16_t sPoH[16 * 136];
  __shared__ __align__(16) bf16_t sPoL[16 * 136];
  __shared__ __align__(16) bf16_t sGo[128 * 24];

  int tid = threadIdx.x, lane = tid & 63, wv = tid >> 6;
  int qd = lane >> 4, ln = lane & 15, kq = qd * 8;

  bf16x8 Bp[8], Bg[8];
  {
    const bf16_t* bp = phwb + (wv * 16 + ln) * 256;
    const bf16_t* bg = gwb + (wv * 16 + ln) * 256;
    #pragma unroll
    for (int c = 0; c < 8; ++c) {
      Bp[c] = *(const bf16x8*)(bp + c * 32 + kq);
      Bg[c] = *(const bf16x8*)(bg + c * 32 + kq);
    }
  }

  {
    int mq = tid & 15, c0 = tid >> 4;
    int ma = (mq >> 3) * 128 + (mq & 7) * 4;
    #pragma unroll
    for (int it = 0; it < 16; ++it) {
      int c = it * 16 + c0;
      float v[4];
      ld4(xin, xb + (long)c * 16384 + ma, isbf, v);
      #pragma unroll
      for (int r = 0; r < 4; ++r) {
        int m = mq * 4 + r;
        int s = (((m >> 2) ^ m) & 7) << 3;
        sX[m * 256 + (c ^ s)] = f2b(v[r]);
      }
    }
  }
  __syncthreads();

  #pragma unroll
  for (int h = 0; h < 2; ++h) {
    if (h == 1) {
      const bf16_t* bp = phwb + ((wv + 4) * 16 + ln) * 256;
      const bf16_t* bg = gwb + ((wv + 4) * 16 + ln) * 256;
      #pragma unroll
      for (int c = 0; c < 8; ++c) {
        Bp[c] = *(const bf16x8*)(bp + c * 32 + kq);
        Bg[c] = *(const bf16x8*)(bg + c * 32 + kq);
      }
    }
    f32x4 accP[4], accG[4];
    #pragma unroll
    for (int mb = 0; mb < 4; ++mb) {
      int row = mb * 16 + ln;
      int s = (((row >> 2) ^ row) & 7) << 3;
      bf16x8 af[8];
      #pragma unroll
      for (int c = 0; c < 8; ++c)
        af[c] = *(const bf16x8*)(sX + row * 256 + ((c * 32 + kq) ^ s));
      f32x4 ap = {0.f,0.f,0.f,0.f}, ag = {0.f,0.f,0.f,0.f};
      #pragma unroll
      for (int c = 0; c < 8; ++c) {
        ap = mfma(af[c], Bp[c], ap);
        ag = mfma(af[c], Bg[c], ag);
      }
      accP[mb] = ap; accG[mb] = ag;
    }
    int o = (wv + h * 4) * 16 + ln;
    float pb = ldin(phb, o, isbf), gb2 = ldin(gbb, o, isbf);
    #pragma unroll
    for (int mb2 = 0; mb2 < 2; ++mb2)
      #pragma unroll
      for (int r = 0; r < 4; r += 2) {
        float v = fmaxf(fmaxf(accP[mb2][r], accP[mb2][r + 1]),
                        fmaxf(accP[mb2 + 2][r], accP[mb2 + 2][r + 1]));
        float u = fmaxf(fmaxf(accG[mb2][r], accG[mb2][r + 1]),
                        fmaxf(accG[mb2 + 2][r], accG[mb2 + 2][r + 1]));
        int cp = mb2 * 8 + qd * 2 + (r >> 1);
        float pv = v + pb;
        bf16_t hi = f2b(pv);
        sPoH[cp * 136 + o] = hi;
        sPoL[cp * 136 + o] = f2b(pv - b2f(hi));
        sGo[o * 24 + cp] = f2b(u + gb2);
      }
  }
  __syncthreads();

  {
    int kp = tid >> 4, seg = tid & 15;
    long base = (long)tile * 32768 + (long)(j * 16 + kp) * 128 + seg * 8;
    *(uint4*)(phiH + base) = *(const uint4*)(sPoH + kp * 136 + seg * 8);
    *(uint4*)(phiL + base) = *(const uint4*)(sPoL + kp * 136 + seg * 8);
  }
  {
    int o = tid >> 1, sg = tid & 1;
    *(uint4*)(gT + (long)tile * 32768 + (long)o * 256 + j * 16 + sg * 8) =
        *(const uint4*)(sGo + o * 24 + sg * 8);
  }
}

// ---- K2: uniform 16-chunk double-buffered pipeline, raw barriers (no vmcnt drains) ----
// LDS map (49664 B):
//  [0..32768)      stage: 2 x 16KB slots (phi: hi@+0/lo@+4096el [32][128]swz;
//                  g [32][256]swz; ww [64][128]swz). sX [32][512] aliases here.
//  [32768..49152)  sTh [32][128]swz + sTl [32][128]swz; sF [32][256]swz aliases;
//                  sY [32][128]swz aliases sF lower half (sF dead after Fa read).
//  [49152..49664)  sredM/sredS
__global__ __launch_bounds__(256, 3) void k2(const void* xin, const bf16_t* thwb,
    const void* thb, const bf16_t* phiH, const bf16_t* phiL, const bf16_t* gT,
    const bf16_t* wwb, const float* sc, const float* sh, void* outv, const int* flag) {
  int isbf = *flag;
  int wg = (blockIdx.x & 7) * 512 + (blockIdx.x >> 3);  // XCD swizzle, 4096%8==0
  int tile = wg >> 5, qb = wg & 31;
  int bi = tile >> 4, t16 = tile & 15, ty = t16 >> 2, tx = t16 & 3;
  long xbase = (long)bi * 256 * 16384 + (long)(ty * 32 + qb) * 128 + tx * 32;

  __shared__ __align__(16) char smem[49664];
  bf16_t* stage = (bf16_t*)smem;
  bf16_t* sX  = (bf16_t*)smem;
  bf16_t* sTh = (bf16_t*)(smem + 32768);
  bf16_t* sTl = (bf16_t*)(smem + 40960);
  bf16_t* sF  = (bf16_t*)(smem + 32768);
  bf16_t* sY  = (bf16_t*)(smem + 32768);
  float* sredM = (float*)(smem + 49152);
  float* sredS = (float*)(smem + 49408);

  int tid = threadIdx.x, lane = tid & 63, wv = tid >> 6;
  int qd = lane >> 4, ln = lane & 15, kq = qd * 8;
  int ms = wv >> 1, half = wv & 1;
  int m0 = ms * 16 + qd * 4;

  // staging coordinates
  int pr = tid >> 4, pc = (tid & 15) * 8, pswz = (pr & 7) << 3;   // 128-wide
  int gr = tid >> 5, gc = (tid & 31) * 8, gswz = (gr & 7) << 3;   // 256-wide
  int brow = half * 16 + ln, bswz = (brow & 7) << 3;

  const bf16_t* PH = phiH + (long)tile * 32768;
  const bf16_t* PL = phiL + (long)tile * 32768;
  const bf16_t* GG = gT + (long)tile * 32768;

#define ISSUE(cc, pf)                                              \
  do {                                                             \
    if ((cc) < 8) {                                                \
      const bf16_t* p_ = PH + (cc) * 4096;                         \
      const bf16_t* q_ = PL + (cc) * 4096;                         \
      pf[0] = *(const uint4*)(p_ + tid * 8);                       \
      pf[1] = *(const uint4*)(p_ + 2048 + tid * 8);                \
      pf[2] = *(const uint4*)(q_ + tid * 8);                       \
      pf[3] = *(const uint4*)(q_ + 2048 + tid * 8);                \
    } else if ((cc) < 12) {                                        \
      const bf16_t* p_ = GG + ((cc) - 8) * 8192;                   \
      pf[0] = *(const uint4*)(p_ + tid * 8);                       \
      pf[1] = *(const uint4*)(p_ + 2048 + tid * 8);                \
      pf[2] = *(const uint4*)(p_ + 4096 + tid * 8);                \
      pf[3] = *(const uint4*)(p_ + 6144 + tid * 8);                \
    } else if ((cc) < 16) {                                        \
      const bf16_t* p_ = wwb + ((cc) - 12) * 8192;                 \
      pf[0] = *(const uint4*)(p_ + tid * 8);                       \
      pf[1] = *(const uint4*)(p_ + 2048 + tid * 8);                \
      pf[2] = *(const uint4*)(p_ + 4096 + tid * 8);                \
      pf[3] = *(const uint4*)(p_ + 6144 + tid * 8);                \
    }                                                              \
  } while (0)

#define WPHI(sl, pf)                                               \
  do {                                                             \
    *(uint4*)((sl) + pr * 128 + (pc ^ pswz)) = pf[0];              \
    *(uint4*)((sl) + (pr + 16) * 128 + (pc ^ pswz)) = pf[1];       \
    *(uint4*)((sl) + 4096 + pr * 128 + (pc ^ pswz)) = pf[2];       \
    *(uint4*)((sl) + 4096 + (pr + 16) * 128 + (pc ^ pswz)) = pf[3];\
  } while (0)

#define WG(sl, pf)                                                 \
  do {                                                             \
    *(uint4*)((sl) + gr * 256 + (gc ^ gswz)) = pf[0];              \
    *(uint4*)((sl) + (gr + 8) * 256 + (gc ^ gswz)) = pf[1];        \
    *(uint4*)((sl) + (gr + 16) * 256 + (gc ^ gswz)) = pf[2];       \
    *(uint4*)((sl) + (gr + 24) * 256 + (gc ^ gswz)) = pf[3];       \
  } while (0)

#define WW(sl, pf)                                                 \
  do {                                                             \
    *(uint4*)((sl) + pr * 128 + (pc ^ pswz)) = pf[0];              \
    *(uint4*)((sl) + (pr + 16) * 128 + (pc ^ pswz)) = pf[1];       \
    *(uint4*)((sl) + (pr + 32) * 128 + (pc ^ pswz)) = pf[2];       \
    *(uint4*)((sl) + (pr + 48) * 128 + (pc ^ pswz)) = pf[3];       \
  } while (0)

  // ---- x slab -> sX [hi|lo], swizzled ----
  {
    int wq = tid & 7, c0 = tid >> 3;
    #pragma unroll
    for (int it = 0; it < 8; ++it) {
      int cch = it * 32 + c0;
      float v[4];
      ld4(xin, xbase + (long)cch * 16384 + wq * 4, isbf, v);
      #pragma unroll
      for (int r = 0; r < 4; ++r) {
        int m = wq * 4 + r;
        int s = (((m >> 2) ^ m) & 7) << 3;
        int cs = cch ^ s;
        bf16_t hi = f2b(v[r]);
        sX[m * 512 + cs] = hi;
        sX[m * 512 + 256 + cs] = f2b(v[r] - b2f(hi));
      }
    }
  }
  lbar();

  // ---- theta = Xhi @ thw -> sTh/sTl (swizzled), chains split 2x4 ----
  {
    bf16x8 Axf[8];
    #pragma unroll
    for (int t = 0; t < 4; ++t) {
      int tms = t >> 1, tns = (t & 1) * 4 + wv;
      if ((t & 1) == 0) {
        int row = tms * 16 + ln;
        int s = (((row >> 2) ^ row) & 7) << 3;
        #pragma unroll
        for (int c = 0; c < 8; ++c)
          Axf[c] = *(const bf16x8*)(sX + row * 512 + ((c * 32 + kq) ^ s));
      }
      const bf16_t* B = thwb + (tns * 16 + ln) * 256;
      f32x4 t0 = {0.f,0.f,0.f,0.f}, t1 = {0.f,0.f,0.f,0.f};
      #pragma unroll
      for (int c = 0; c < 8; ++c) {
        bf16x8 bw = *(const bf16x8*)(B + c * 32 + kq);
        if (c < 4) t0 = mfma(Axf[c], bw, t0);
        else       t1 = mfma(Axf[c], bw, t1);
      }
      f32x4 a = t0 + t1;
      float bias = ldin(thb, tns * 16 + ln, isbf);
      #pragma unroll
      for (int r = 0; r < 4; ++r) {
        float v = a[r] + bias;
        bf16_t hi = f2b(v);
        int mrow = tms * 16 + qd * 4 + r;
        int col = (tns * 16 + ln) ^ ((mrow & 7) << 3);
        sTh[mrow * 128 + col] = hi;
        sTl[mrow * 128 + col] = f2b(v - b2f(hi));
      }
    }
  }

  // issue chunks 0,1 (ride through the next barrier)
  uint4 pfA[4], pfB[4];
  ISSUE(0, pfA);
  ISSUE(1, pfB);

  // ---- residual extract from sX (mapping matches wy consumer) ----
  f32x4 xres[8];
  #pragma unroll
  for (int c4 = 0; c4 < 4; ++c4) {
    #pragma unroll
    for (int jj = 0; jj < 2; ++jj) {
      int o = c4 * 64 + (half * 2 + jj) * 16 + ln;
      f32x4 xr;
      #pragma unroll
      for (int r = 0; r < 4; ++r) {
        int row = m0 + r;
        int s = (((row >> 2) ^ row) & 7) << 3;
        int cs = o ^ s;
        xr[r] = b2f(sX[row * 512 + cs]) + b2f(sX[row * 512 + 256 + cs]);
      }
      xres[c4 * 2 + jj] = xr;
    }
  }
  lbar();   // sX dead; sTh/sTl published

  // theta A-frags
  bf16x8 Ah[4], Al[4];
  {
    int row = ms * 16 + ln, sw = (row & 7) << 3;
    #pragma unroll
    for (int c = 0; c < 4; ++c) {
      Ah[c] = *(const bf16x8*)(sTh + row * 128 + ((c * 32 + kq) ^ sw));
      Al[c] = *(const bf16x8*)(sTl + row * 128 + ((c * 32 + kq) ^ sw));
    }
  }

  // ---- S = theta @ phi^T: chunks 0..7, dbuf, one barrier per chunk ----
  f32x4 S[8];
  #pragma unroll
  for (int c = 0; c < 8; ++c) {
    bf16_t* sl = stage + (c & 1) * 8192;
    if (c & 1) { WPHI(sl, pfB); ISSUE(c + 2, pfB); }
    else       { WPHI(sl, pfA); ISSUE(c + 2, pfA); }
    lbar();
    const bf16_t* Bh = sl + brow * 128;
    const bf16_t* Bl = sl + 4096 + brow * 128;
    f32x4 a0 = {0.f,0.f,0.f,0.f}, a1 = {0.f,0.f,0.f,0.f};
    #pragma unroll
    for (int kk = 0; kk < 4; ++kk) {
      int co = (kk * 32 + kq) ^ bswz;
      bf16x8 bh = *(const bf16x8*)(Bh + co);
      bf16x8 bl = *(const bf16x8*)(Bl + co);
      if (kk < 2) {
        a0 = mfma(Ah[kk], bl, a0); a0 = mfma(Al[kk], bh, a0); a0 = mfma(Ah[kk], bh, a0);
      } else {
        a1 = mfma(Ah[kk], bl, a1); a1 = mfma(Al[kk], bh, a1); a1 = mfma(Ah[kk], bh, a1);
      }
    }
    S[c] = a0 + a1;
  }

  // ---- register softmax (raw barriers: g prefetch stays in flight) ----
  float Mr[4], Sr[4], inv4[4];
  #pragma unroll
  for (int r = 0; r < 4; ++r) {
    float m = S[0][r];
    #pragma unroll
    for (int t = 1; t < 8; ++t) m = fmaxf(m, S[t][r]);
    #pragma unroll
    for (int d = 1; d < 16; d <<= 1) m = fmaxf(m, __shfl_xor(m, d, 64));
    Mr[r] = m;
  }
  if (ln == 0) {
    #pragma unroll
    for (int r = 0; r < 4; ++r) sredM[(m0 + r) * 2 + half] = Mr[r];
  }
  lbar();
  #pragma unroll
  for (int r = 0; r < 4; ++r) Mr[r] = fmaxf(Mr[r], sredM[(m0 + r) * 2 + (half ^ 1)]);
  #pragma unroll
  for (int r = 0; r < 4; ++r) {
    float s = 0.f;
    #pragma unroll
    for (int t = 0; t < 8; ++t) { float e = __expf(S[t][r] - Mr[r]); S[t][r] = e; s += e; }
    #pragma unroll
    for (int d = 1; d < 16; d <<= 1) s += __shfl_xor(s, d, 64);
    Sr[r] = s;
  }
  if (ln == 0) {
    #pragma unroll
    for (int r = 0; r < 4; ++r) sredS[(m0 + r) * 2 + half] = Sr[r];
  }
  lbar();
  #pragma unroll
  for (int r = 0; r < 4; ++r) inv4[r] = 1.f / (Sr[r] + sredS[(m0 + r) * 2 + (half ^ 1)]);

  // F -> sF (swizzled; aliases sTh/sTl, theta frags in regs)
  #pragma unroll
  for (int c = 0; c < 8; ++c) {
    int n = c * 32 + half * 16 + ln;
    #pragma unroll
    for (int r = 0; r < 4; ++r) {
      int row = m0 + r;
      sF[row * 256 + (n ^ ((row & 7) << 3))] = f2b(S[c][r] * inv4[r]);
    }
  }
  lbar();

  bf16x8 Fa[8];
  {
    int row = ms * 16 + ln, sw = (row & 7) << 3;
    #pragma unroll
    for (int c = 0; c < 8; ++c)
      Fa[c] = *(const bf16x8*)(sF + row * 256 + ((c * 32 + kq) ^ sw));
  }

  // ---- y = F @ g: chunks 8..11 ----
  #pragma unroll
  for (int ci = 0; ci < 4; ++ci) {
    const int c = 8 + ci;
    bf16_t* sl = stage + (c & 1) * 8192;
    if (c & 1) { WG(sl, pfB); ISSUE(c + 2, pfB); }
    else       { WG(sl, pfA); ISSUE(c + 2, pfA); }
    lbar();
    const bf16_t* Bg = sl + brow * 256;
    f32x4 a0 = {0.f,0.f,0.f,0.f}, a1 = {0.f,0.f,0.f,0.f};
    #pragma unroll
    for (int kk = 0; kk < 8; ++kk) {
      int co = (kk * 32 + kq) ^ bswz;
      bf16x8 bw = *(const bf16x8*)(Bg + co);
      if (kk < 4) a0 = mfma(Fa[kk], bw, a0);
      else        a1 = mfma(Fa[kk], bw, a1);
    }
    f32x4 ya = a0 + a1;
    #pragma unroll
    for (int r = 0; r < 4; ++r) {
      int row = m0 + r;
      int col = ci * 32 + half * 16 + ln;
      sY[row * 128 + (col ^ ((row & 7) << 3))] = f2b(ya[r]);
    }
  }
  lbar();   // sY published (sF dead: Fa in regs)

  bf16x8 Ya[4];
  {
    int row = ms * 16 + ln, sw = (row & 7) << 3;
    #pragma unroll
    for (int kk = 0; kk < 4; ++kk)
      Ya[kk] = *(const bf16x8*)(sY + row * 128 + ((kk * 32 + kq) ^ sw));
  }

  // ---- wy = y @ ww^T + BN + residual: chunks 12..15 ----
  #pragma unroll
  for (int ci = 0; ci < 4; ++ci) {
    const int c = 12 + ci;
    bf16_t* sl = stage + (c & 1) * 8192;
    if (c & 1) { WW(sl, pfB); if (c + 2 < 16) ISSUE(c + 2, pfB); }
    else       { WW(sl, pfA); if (c + 2 < 16) ISSUE(c + 2, pfA); }
    lbar();
    #pragma unroll
    for (int jj = 0; jj < 2; ++jj) {
      int nsL = half * 2 + jj;
      int rw = nsL * 16 + ln;
      int wsw = (rw & 7) << 3;
      const bf16_t* Bw = sl + rw * 128;
      f32x4 a0 = {0.f,0.f,0.f,0.f}, a1 = {0.f,0.f,0.f,0.f};
      #pragma unroll
      for (int kk = 0; kk < 4; ++kk) {
        int co = (kk * 32 + kq) ^ wsw;
        bf16x8 bw = *(const bf16x8*)(Bw + co);
        if (kk < 2) a0 = mfma(Ya[kk], bw, a0);
        else        a1 = mfma(Ya[kk], bw, a1);
      }
      f32x4 a = a0 + a1;
      int o = ci * 64 + nsL * 16 + ln;
      float s2 = sc[o], hh = sh[o];
      f32x4 xr = xres[ci * 2 + jj];
      long oi = (long)tile * 262144 + (long)o * 1024 + qb * 32 + m0;
      if (isbf) {
        unsigned short uu[4];
        #pragma unroll
        for (int r = 0; r < 4; ++r) uu[r] = bbits(f2b(a[r] * s2 + hh + xr[r]));
        __builtin_memcpy((unsigned short*)outv + oi, uu, 8);
      } else {
        float vv[4];
        #pragma unroll
        for (int r = 0; r < 4; ++r) vv[r] = a[r] * s2 + hh + xr[r];
        __builtin_memcpy((float*)outv + oi, vv, 16);
      }
    }
  }
#undef ISSUE
#undef WPHI
#undef WG
#undef WW
}

extern "C" void kernel_launch(void* const* d_in, const int* in_sizes, int n_in,
                              void* d_out, int out_size, void* d_ws, size_t ws_size,
                              hipStream_t stream) {
  (void)in_sizes; (void)n_in; (void)out_size; (void)ws_size;
  const void* x    = d_in[0];
  const void* thwf = d_in[1];
  const void* thb  = d_in[2];
  const void* phw  = d_in[3];
  const void* phb  = d_in[4];
  const void* gwf  = d_in[5];
  const void* gbb  = d_in[6];
  const void* wwf  = d_in[7];
  const void* wb   = d_in[8];
  const void* gma  = d_in[9];
  const void* bta  = d_in[10];
  const void* mn   = d_in[11];
  const void* vr   = d_in[12];

  char* ws = (char*)d_ws;
  bf16_t* thwb = (bf16_t*)(ws);
  bf16_t* phwb = (bf16_t*)(ws + 65536);
  bf16_t* gwb  = (bf16_t*)(ws + 131072);
  bf16_t* wwb  = (bf16_t*)(ws + 196608);
  float*  sc   = (float*)(ws + 262144);
  float*  sh   = (float*)(ws + 263168);
  int*    flag = (int*)(ws + 264192);
  bf16_t* phiH = (bf16_t*)(ws + 264448);
  bf16_t* phiL = (bf16_t*)(ws + 264448 + 8388608);
  bf16_t* gT   = (bf16_t*)(ws + 264448 + 16777216);

  kdetect<<<1, 256, 0, stream>>>((const unsigned int*)x, flag);
  k0<<<128, 256, 0, stream>>>(thwf, phw, gwf, wwf, wb, gma, bta, mn, vr,
                              thwb, phwb, gwb, wwb, sc, sh, flag);
  k1<<<2048, 256, 0, stream>>>(x, phwb, gwb, phb, gbb, phiH, phiL, gT, flag);
  k2<<<4096, 256, 0, stream>>>(x, thwb, thb, phiH, phiL, gT, wwb, sc, sh,
                               d_out, flag);
}